// Round 2
// baseline (307.218 us; speedup 1.0000x reference)
//
#include <hip/hip_runtime.h>
#include <hip/hip_bf16.h>

#define NN 4096
#define FIN 128
#define FOUT 64
#define NH 8
#define LOG2E 1.44269504088896340736f

typedef float f32x4 __attribute__((ext_vector_type(4)));
typedef __bf16 bf16x8 __attribute__((ext_vector_type(8)));
typedef unsigned long long u64;

// ---------------- Kernel 0: fold skip_w over heads: Wf[i][f] = (1/8) sum_h skip_w[h*64+f][i]
__global__ __launch_bounds__(256) void fold_skip_kernel(
    const float* __restrict__ skip_w, float* __restrict__ Wf) {
    int idx = blockIdx.x * 256 + threadIdx.x;   // 8192 = 128*64
    int i = idx >> 6, f = idx & 63;
    float s = 0.f;
#pragma unroll
    for (int h = 0; h < NH; ++h) s += skip_w[(h * FOUT + f) * FIN + i];
    Wf[i * FOUT + f] = 0.125f * s;
}

// ---------------- Kernel 1: per-head projection h = x @ proj[h], emit:
//   Vt[h][f][n] (bf16, transposed for B-fragment loads)
//   ssrc_raw[h][n], sdst_raw[h][n]  (fp32, UNscaled)
__global__ __launch_bounds__(256) void proj_kernel(
    const float* __restrict__ x, const float* __restrict__ proj,
    const float* __restrict__ sw_src, const float* __restrict__ sw_dst,
    __hip_bfloat16* __restrict__ Vt, float* __restrict__ ssrc, float* __restrict__ sdst) {
    __shared__ float ps[FIN][FOUT];        // 32 KB
    __shared__ float xs[32][FIN + 5];      // stride 133 words: conflict-free (5 coprime 32)
    __shared__ float red_s[32], red_d[32];

    const int head = blockIdx.x & 7;
    const int n0 = (blockIdx.x >> 3) * 32;
    const int tid = threadIdx.x;

    const float4* psrc = (const float4*)(proj + (size_t)head * FIN * FOUT);
    float4* pdst = (float4*)&ps[0][0];
    for (int i = tid; i < FIN * FOUT / 4; i += 256) pdst[i] = psrc[i];
    const float4* xsrc = (const float4*)(x + (size_t)n0 * FIN);
    for (int i = tid; i < 32 * FIN / 4; i += 256) {
        int r = i >> 5, c4 = i & 31;
        *(float4*)&xs[r][c4 * 4] = xsrc[i];
    }
    if (tid < 32) { red_s[tid] = 0.f; red_d[tid] = 0.f; }
    __syncthreads();

    const int r = tid & 31;
    const int f0 = (tid >> 5) * 8;
    float acc[8];
#pragma unroll
    for (int j = 0; j < 8; ++j) acc[j] = 0.f;
#pragma unroll 4
    for (int i = 0; i < FIN; ++i) {
        float xv = xs[r][i];
        float4 p0 = *(float4*)&ps[i][f0];
        float4 p1 = *(float4*)&ps[i][f0 + 4];
        acc[0] += xv * p0.x; acc[1] += xv * p0.y; acc[2] += xv * p0.z; acc[3] += xv * p0.w;
        acc[4] += xv * p1.x; acc[5] += xv * p1.y; acc[6] += xv * p1.z; acc[7] += xv * p1.w;
    }
    float pssum = 0.f, pdsum = 0.f;
#pragma unroll
    for (int j = 0; j < 8; ++j) {
        pssum += acc[j] * sw_src[head * FOUT + f0 + j];
        pdsum += acc[j] * sw_dst[head * FOUT + f0 + j];
    }
    atomicAdd(&red_s[r], pssum);
    atomicAdd(&red_d[r], pdsum);
#pragma unroll
    for (int j = 0; j < 8; ++j)
        Vt[((size_t)head * FOUT + f0 + j) * NN + n0 + r] = __float2bfloat16(acc[j]);
    __syncthreads();
    if (tid < 32) {
        ssrc[head * NN + n0 + tid] = red_s[tid];
        sdst[head * NN + n0 + tid] = red_d[tid];
    }
}

// ---------------- Kernel 2: skipm = x @ Wf   (mean-over-heads skip, [N][64] fp32)
__global__ __launch_bounds__(256) void skipm_kernel(
    const float* __restrict__ x, const float* __restrict__ Wf, float* __restrict__ skipm) {
    __shared__ float ws_[FIN][FOUT];
    __shared__ float xs[32][FIN + 5];
    const int n0 = blockIdx.x * 32;
    const int tid = threadIdx.x;
    const float4* psrc = (const float4*)Wf;
    float4* pdst = (float4*)&ws_[0][0];
    for (int i = tid; i < FIN * FOUT / 4; i += 256) pdst[i] = psrc[i];
    const float4* xsrc = (const float4*)(x + (size_t)n0 * FIN);
    for (int i = tid; i < 32 * FIN / 4; i += 256) {
        int r = i >> 5, c4 = i & 31;
        *(float4*)&xs[r][c4 * 4] = xsrc[i];
    }
    __syncthreads();
    const int r = tid & 31;
    const int f0 = (tid >> 5) * 8;
    float acc[8];
#pragma unroll
    for (int j = 0; j < 8; ++j) acc[j] = 0.f;
#pragma unroll 4
    for (int i = 0; i < FIN; ++i) {
        float xv = xs[r][i];
        float4 p0 = *(float4*)&ws_[i][f0];
        float4 p1 = *(float4*)&ws_[i][f0 + 4];
        acc[0] += xv * p0.x; acc[1] += xv * p0.y; acc[2] += xv * p0.z; acc[3] += xv * p0.w;
        acc[4] += xv * p1.x; acc[5] += xv * p1.y; acc[6] += xv * p1.z; acc[7] += xv * p1.w;
    }
#pragma unroll
    for (int j = 0; j < 8; ++j)
        skipm[(size_t)(n0 + r) * FOUT + f0 + j] = acc[j];
}

// ---------------- Kernel 3: d-prep: d1[h][j] = log2e*sdst_raw, maxd[h] = max_j sdst_raw
__global__ __launch_bounds__(256) void dprep_kernel(
    const float* __restrict__ sdst_raw, float* __restrict__ d1, float* __restrict__ maxd) {
    const int h = blockIdx.x;
    const float* s = sdst_raw + h * NN;
    float mx = -INFINITY;
    for (int i = threadIdx.x; i < NN; i += 256) {
        float v = s[i];
        d1[h * NN + i] = LOG2E * v;
        mx = fmaxf(mx, v);
    }
#pragma unroll
    for (int o = 32; o >= 1; o >>= 1) mx = fmaxf(mx, __shfl_xor(mx, o));
    __shared__ float red[4];
    if ((threadIdx.x & 63) == 0) red[threadIdx.x >> 6] = mx;
    __syncthreads();
    if (threadIdx.x == 0) maxd[h] = fmaxf(fmaxf(red[0], red[1]), fmaxf(red[2], red[3]));
}

// ---------------- Kernel 4: per-row constants. M_i = LR(si + maxd) is a safe upper
// bound on max_j (LR(si+dj)+topo) because LR is monotone; exp2 args are always <= 0.
__global__ __launch_bounds__(256) void arow_kernel(
    const float* __restrict__ ssrc_raw, const float* __restrict__ maxd,
    float* __restrict__ a1, float* __restrict__ a2) {
    int idx = blockIdx.x * 256 + threadIdx.x;   // 32768
    int h = idx >> 12;
    float si = ssrc_raw[idx];
    float t = si + maxd[h];
    float M = fmaxf(t, 0.2f * t);
    a1[idx] = LOG2E * (si - M);
    a2[idx] = LOG2E * (0.2f * si - M);
}

// ---------------- Kernel 5: topology -> bitmask (bit=1 where edge). 67MB -> 2MB.
__global__ __launch_bounds__(256) void mask_kernel(
    const float* __restrict__ topo, u64* __restrict__ mb) {
    const int gw = blockIdx.x * 4 + (threadIdx.x >> 6);  // 0..4095
    const int lane = threadIdx.x & 63;
    for (int it = 0; it < 64; ++it) {
        size_t u = (size_t)it * 4096 + gw;               // u64 index 0..262143
        float t = topo[u * 64 + lane];
        u64 b = __ballot(t > -0.5e9f);
        if (lane == 0) mb[u] = b;
    }
}

// ---------------- Kernel 6: attention. 256 blocks x 512 thr; wave = head; Q-tile 16 rows.
// No barriers in K-loop; fixed row-max bound; bitmask topology; ping-pong prefetch.
__global__ __launch_bounds__(512) void attn_kernel(
    const u64* __restrict__ maskbits, const __hip_bfloat16* __restrict__ Vt_,
    const float* __restrict__ d1, const float* __restrict__ a1v, const float* __restrict__ a2v,
    const float* __restrict__ skipm, float* __restrict__ out) {
    __shared__ char smem[NH * 16 * 68 * 4];              // 34816 B; mask aliases front
    u64 (*maskS)[67] = (u64(*)[67])smem;                 // 16*67*8 = 8576 B
    float (*stageO)[16][68] = (float(*)[16][68])smem;

    const int tid = threadIdx.x;
    const int wave = tid >> 6;               // = head
    const int lane = tid & 63;
    const int q = lane >> 4;
    const int li = lane & 15;
    const int q0 = blockIdx.x * 16;

    // stage this block's 16 mask rows (8KB) once
    for (int t = tid; t < 1024; t += 512) {
        int row = t >> 6, kt = t & 63;
        maskS[row][kt] = maskbits[(size_t)(q0 + row) * 64 + kt];
    }
    __syncthreads();

    const __bf16* vbase = reinterpret_cast<const __bf16*>(Vt_) + (size_t)wave * FOUT * NN;
    const float* dbase = d1 + wave * NN;
    const float A1 = a1v[wave * NN + q0 + li];
    const float A2 = a2v[wave * NN + q0 + li];

    float rs = 0.f;
    f32x4 acc[4];
#pragma unroll
    for (int n = 0; n < 4; ++n) acc[n] = (f32x4){0.f, 0.f, 0.f, 0.f};

    auto load_tile = [&](int kt, float4* dv, bf16x8 (*vfv)[4]) {
        const float* dp = dbase + kt * 64 + q * 8;
        dv[0] = *(const float4*)(dp);
        dv[1] = *(const float4*)(dp + 4);
        dv[2] = *(const float4*)(dp + 32);
        dv[3] = *(const float4*)(dp + 36);
#pragma unroll
        for (int n = 0; n < 4; ++n) {
            const __bf16* vp = vbase + (size_t)(n * 16 + li) * NN + kt * 64 + q * 8;
            vfv[0][n] = *(const bf16x8*)(vp);
            vfv[1][n] = *(const bf16x8*)(vp + 32);
        }
    };

    float4 cd[4]; bf16x8 cvf[2][4];
    load_tile(0, cd, cvf);

    for (int kt = 0; kt < 64; ++kt) {
        float4 nd[4]; bf16x8 nvf[2][4];
        load_tile((kt + 1) & 63, nd, nvf);   // wraps on last iter; harmless

        u64 mw = maskS[li][kt];
        unsigned mlo = (unsigned)(mw >> (q * 8)) & 0xffu;
        unsigned mhi = (unsigned)(mw >> (q * 8 + 32)) & 0xffu;
        const float* dvf = (const float*)cd;
        bf16x8 pf[2];
#pragma unroll
        for (int c = 0; c < 2; ++c) {
            unsigned mm = c ? mhi : mlo;
#pragma unroll
            for (int j = 0; j < 8; ++j) {
                float dj = dvf[c * 8 + j];
                float e1 = A1 + dj;
                float e2 = fmaf(0.2f, dj, A2);
                float lr = fmaxf(e1, e2);
                float pv = exp2f(lr);            // lr <= 0 always
                pv = ((mm >> j) & 1u) ? pv : 0.f;
                rs += pv;
                pf[c][j] = (__bf16)pv;
            }
        }
#pragma unroll
        for (int c = 0; c < 2; ++c)
#pragma unroll
            for (int n = 0; n < 4; ++n)
                acc[n] = __builtin_amdgcn_mfma_f32_16x16x32_bf16(pf[c], cvf[c][n], acc[n], 0, 0, 0);

#pragma unroll
        for (int u = 0; u < 4; ++u) cd[u] = nd[u];
#pragma unroll
        for (int c = 0; c < 2; ++c)
#pragma unroll
            for (int n = 0; n < 4; ++n) cvf[c][n] = nvf[c][n];
    }

    // row sums: reduce across q (lanes differing in bits 4..5)
    rs += __shfl_xor(rs, 16);
    rs += __shfl_xor(rs, 32);
    // C-layout row = q*4+reg; lane (q*4+reg) holds that row's l (its li == q*4+reg)
    float r0 = 1.f / __shfl(rs, q * 4 + 0);
    float r1 = 1.f / __shfl(rs, q * 4 + 1);
    float r2 = 1.f / __shfl(rs, q * 4 + 2);
    float r3 = 1.f / __shfl(rs, q * 4 + 3);

    __syncthreads();   // all mask reads done before stageO overwrites smem
#pragma unroll
    for (int n = 0; n < 4; ++n) {
        stageO[wave][q * 4 + 0][n * 16 + li] = acc[n][0] * r0;
        stageO[wave][q * 4 + 1][n * 16 + li] = acc[n][1] * r1;
        stageO[wave][q * 4 + 2][n * 16 + li] = acc[n][2] * r2;
        stageO[wave][q * 4 + 3][n * 16 + li] = acc[n][3] * r3;
    }
    __syncthreads();

    {
        int e = tid * 2;
        int rr = e >> 6, cc = e & 63;
        float s0 = 0.f, s1 = 0.f;
#pragma unroll
        for (int h = 0; h < NH; ++h) {
            s0 += stageO[h][rr][cc];
            s1 += stageO[h][rr][cc + 1];
        }
        float2 sk = *(const float2*)&skipm[(size_t)(q0 + rr) * FOUT + cc];
        float v0 = s0 * 0.125f + sk.x;
        float v1 = s1 * 0.125f + sk.y;
        v0 = fmaxf(v0, 0.2f * v0);
        v1 = fmaxf(v1, 0.2f * v1);
        float2 o = {v0, v1};
        *(float2*)&out[(size_t)(q0 + rr) * FOUT + cc] = o;
    }
}

extern "C" void kernel_launch(void* const* d_in, const int* in_sizes, int n_in,
                              void* d_out, int out_size, void* d_ws, size_t ws_size,
                              hipStream_t stream) {
    (void)in_sizes; (void)n_in; (void)out_size; (void)ws_size;
    const float* x         = (const float*)d_in[0];   // [4096,128]
    const float* topology  = (const float*)d_in[1];   // [4096,4096]
    const float* proj      = (const float*)d_in[2];   // [8,128,64]
    const float* score_src = (const float*)d_in[3];   // [8,64]
    const float* score_dst = (const float*)d_in[4];   // [8,64]
    const float* skip_w    = (const float*)d_in[5];   // [512,128]
    float* out = (float*)d_out;                       // [4096,64]

    char* ws = (char*)d_ws;
    __hip_bfloat16* Vt = (__hip_bfloat16*)ws;                 // 4 MB
    float* ssrc_raw = (float*)(ws + 4194304);                 // 128 KB
    float* sdst_raw = (float*)(ws + 4325376);                 // 128 KB
    float* d1       = (float*)(ws + 4456448);                 // 128 KB
    float* a1       = (float*)(ws + 4587520);                 // 128 KB
    float* a2       = (float*)(ws + 4718592);                 // 128 KB
    float* maxd     = (float*)(ws + 4849664);                 // 4 KB pad
    float* Wf       = (float*)(ws + 4853760);                 // 32 KB
    float* skipm    = (float*)(ws + 4886528);                 // 1 MB
    u64* maskbits   = (u64*)(ws + 5935104);                   // 2 MB  (end ~7.66 MB)

    fold_skip_kernel<<<32, 256, 0, stream>>>(skip_w, Wf);
    proj_kernel<<<1024, 256, 0, stream>>>(x, proj, score_src, score_dst, Vt, ssrc_raw, sdst_raw);
    skipm_kernel<<<128, 256, 0, stream>>>(x, Wf, skipm);
    dprep_kernel<<<8, 256, 0, stream>>>(sdst_raw, d1, maxd);
    arow_kernel<<<128, 256, 0, stream>>>(ssrc_raw, maxd, a1, a2);
    mask_kernel<<<1024, 256, 0, stream>>>(topology, maskbits);
    attn_kernel<<<256, 512, 0, stream>>>(maskbits, Vt, d1, a1, a2, skipm, out);
}

// Round 3
// 274.618 us; speedup vs baseline: 1.1187x; 1.1187x over previous
//
#include <hip/hip_runtime.h>
#include <hip/hip_bf16.h>

#define NN 4096
#define FIN 128
#define FOUT 64
#define NH 8
#define LOG2E 1.44269504088896340736f

typedef float f32x4 __attribute__((ext_vector_type(4)));
typedef __bf16 bf16x8 __attribute__((ext_vector_type(8)));
typedef unsigned long long u64;

// ---------------- K0: build combined weights Wc[128][80]:
// cols 0..7 = w_s[h][i] = proj[h]@score_src[h]; 8..15 = w_d; 16..79 = Wf (head-folded skip/8)
__global__ __launch_bounds__(256) void wc_kernel(
    const float* __restrict__ proj, const float* __restrict__ score_src,
    const float* __restrict__ score_dst, const float* __restrict__ skip_w,
    float* __restrict__ Wc) {
    int idx = blockIdx.x * 256 + threadIdx.x;
    if (idx >= FIN * 80) return;
    int i = idx / 80, c = idx % 80;
    float v = 0.f;
    if (c < 16) {
        int h = c & 7;
        const float* w = (c < 8 ? score_src : score_dst) + h * FOUT;
        const float* p = proj + (size_t)h * FIN * FOUT + (size_t)i * FOUT;
        for (int f = 0; f < FOUT; ++f) v += p[f] * w[f];
    } else {
        int f = c - 16;
        for (int h = 0; h < NH; ++h) v += skip_w[(size_t)(h * FOUT + f) * FIN + i];
        v *= 0.125f;
    }
    Wc[i * 80 + c] = v;
}

// ---------------- K1: fp32 GEMM x@Wc -> skipm (into d_out), ssrc, sdst; also casts x->xb (bf16)
__global__ __launch_bounds__(256) void scores_kernel(
    const float* __restrict__ x, const float* __restrict__ Wc,
    float* __restrict__ skipm, float* __restrict__ ssrc, float* __restrict__ sdst,
    __hip_bfloat16* __restrict__ xb_) {
    __shared__ float wcs[FIN][80];     // 40 KB
    __shared__ float xs[32][FIN + 5];  // 17 KB
    const int n0 = blockIdx.x * 32;
    const int tid = threadIdx.x;
    for (int i = tid; i < FIN * 80 / 4; i += 256)
        ((float4*)&wcs[0][0])[i] = ((const float4*)Wc)[i];
    const float4* xsrc = (const float4*)(x + (size_t)n0 * FIN);
    for (int i = tid; i < 32 * FIN / 4; i += 256) {
        int r = i >> 5, c4 = i & 31;
        *(float4*)&xs[r][c4 * 4] = xsrc[i];
    }
    __syncthreads();
    const int r = tid & 31;
    const int g = tid >> 5;        // 0..7
    const int f0 = g * 8;          // skip cols (of 64)
    const int c0 = g * 2;          // score cols (of 16)
    float acc[8];
    float sa0 = 0.f, sa1 = 0.f;
#pragma unroll
    for (int j = 0; j < 8; ++j) acc[j] = 0.f;
#pragma unroll 4
    for (int i = 0; i < FIN; ++i) {
        float xv = xs[r][i];
        float4 p0 = *(float4*)&wcs[i][16 + f0];
        float4 p1 = *(float4*)&wcs[i][16 + f0 + 4];
        float2 q0 = *(float2*)&wcs[i][c0];
        acc[0] += xv * p0.x; acc[1] += xv * p0.y; acc[2] += xv * p0.z; acc[3] += xv * p0.w;
        acc[4] += xv * p1.x; acc[5] += xv * p1.y; acc[6] += xv * p1.z; acc[7] += xv * p1.w;
        sa0 += xv * q0.x; sa1 += xv * q0.y;
    }
    int n = n0 + r;
#pragma unroll
    for (int j = 0; j < 8; ++j) skipm[(size_t)n * FOUT + f0 + j] = acc[j];
    if (c0 < 8) { ssrc[c0 * NN + n] = sa0; ssrc[(c0 + 1) * NN + n] = sa1; }
    else        { sdst[(c0 - 8) * NN + n] = sa0; sdst[(c0 - 7) * NN + n] = sa1; }
    // x -> bf16 cast: thread handles 16 consecutive elems of one row
    {
        int row = tid >> 3, col0 = (tid & 7) * 16;
        const float* src = &xs[row][col0];
        bf16x8 b0, b1;
#pragma unroll
        for (int j = 0; j < 8; ++j) { b0[j] = (__bf16)src[j]; b1[j] = (__bf16)src[8 + j]; }
        __bf16* dst = (__bf16*)xb_ + (size_t)(n0 + row) * FIN + col0;
        *(bf16x8*)dst = b0;
        *(bf16x8*)(dst + 8) = b1;
    }
}

// ---------------- K2: per-head prep: d1 = log2e*sdst; a1/a2 from ssrc with bound M = LR(si+maxd)
__global__ __launch_bounds__(256) void headprep_kernel(
    const float* __restrict__ ssrc, const float* __restrict__ sdst,
    float* __restrict__ d1, float* __restrict__ a1, float* __restrict__ a2) {
    const int h = blockIdx.x;
    const int tid = threadIdx.x;
    float mx = -INFINITY;
    for (int e = tid; e < NN; e += 256) mx = fmaxf(mx, sdst[h * NN + e]);
#pragma unroll
    for (int o = 32; o >= 1; o >>= 1) mx = fmaxf(mx, __shfl_xor(mx, o));
    __shared__ float red[4];
    if ((tid & 63) == 0) red[tid >> 6] = mx;
    __syncthreads();
    float maxd = fmaxf(fmaxf(red[0], red[1]), fmaxf(red[2], red[3]));
    for (int e = tid; e < NN; e += 256) {
        float sd = sdst[h * NN + e];
        d1[h * NN + e] = LOG2E * sd;
        float si = ssrc[h * NN + e];
        float t = si + maxd;
        float M = fmaxf(t, 0.2f * t);
        a1[h * NN + e] = LOG2E * (si - M);
        a2[h * NN + e] = LOG2E * (0.2f * si - M);
    }
}

// ---------------- K3: topology -> bitmask, contiguous streaming (each wave: 8 KB run)
__global__ __launch_bounds__(256) void mask_kernel(
    const float* __restrict__ topo, u64* __restrict__ mb) {
    const int w = blockIdx.x * 4 + (threadIdx.x >> 6);   // 0..8191
    const int lane = threadIdx.x & 63;
    size_t base = (size_t)w * 32;
    for (int it = 0; it < 32; ++it) {
        size_t u = base + it;
        float t = topo[u * 64 + lane];
        u64 b = __ballot(t > -0.5e9f);
        if (lane == 0) mb[u] = b;
    }
}

// ---------------- K4: Vt[h][f][n] = (proj[h]^T @ x^T) via bf16 MFMA
__global__ __launch_bounds__(256) void vt_kernel(
    const float* __restrict__ proj, const __hip_bfloat16* __restrict__ xb_,
    __hip_bfloat16* __restrict__ Vt_) {
    __shared__ __bf16 pT[FOUT][FIN + 8];   // 17.4 KB, row stride 272 B (16B-aligned)
    const int tid = threadIdx.x;
    const int h = blockIdx.x >> 6;
    const int ng = blockIdx.x & 63;
    const __bf16* xb = (const __bf16*)xb_;
    __bf16* Vt = (__bf16*)Vt_;
    for (int idx = tid; idx < FIN * FOUT; idx += 256) {
        int i = idx >> 6, f = idx & 63;
        pT[f][i] = (__bf16)proj[(size_t)h * FIN * FOUT + idx];
    }
    __syncthreads();
    const int wave = tid >> 6, lane = tid & 63, q = lane >> 4, li = lane & 15;
    const int nb = ng * 64 + wave * 16;
    f32x4 acc[4];
#pragma unroll
    for (int n = 0; n < 4; ++n) acc[n] = (f32x4){0.f, 0.f, 0.f, 0.f};
#pragma unroll
    for (int kt = 0; kt < 4; ++kt) {
        bf16x8 bfrag = *(const bf16x8*)(xb + (size_t)(nb + li) * FIN + kt * 32 + q * 8);
#pragma unroll
        for (int ft = 0; ft < 4; ++ft) {
            bf16x8 afrag = *(const bf16x8*)&pT[ft * 16 + li][kt * 32 + q * 8];
            acc[ft] = __builtin_amdgcn_mfma_f32_16x16x32_bf16(afrag, bfrag, acc[ft], 0, 0, 0);
        }
    }
#pragma unroll
    for (int ft = 0; ft < 4; ++ft)
#pragma unroll
        for (int reg = 0; reg < 4; ++reg)
            Vt[((size_t)h * FOUT + ft * 16 + q * 4 + reg) * NN + nb + li] = (__bf16)acc[ft][reg];
}

// ---------------- K5: attention. 256 blocks x 1024 thr = 16 waves: wave = (head, K-half).
// In-block K-half + head combine. 4 waves/SIMD; V ping-pong in regs (128-VGPR cap).
__global__ __launch_bounds__(1024, 4) void attn_kernel(
    const u64* __restrict__ maskbits, const __hip_bfloat16* __restrict__ Vt_,
    const float* __restrict__ d1, const float* __restrict__ a1v, const float* __restrict__ a2v,
    const float* __restrict__ skipm, float* __restrict__ out) {
    __shared__ u64 maskS[16][65];          // 8.3 KB, conflict-free (2li banks)
    __shared__ float rsL[16][17];
    __shared__ float stageB[NH][16][68];   // 34.8 KB
    const int tid = threadIdx.x;
    const int w = tid >> 6;                // 0..15
    const int h = w >> 1, kh = w & 1;
    const int lane = tid & 63, q = lane >> 4, li = lane & 15;
    const int q0 = blockIdx.x * 16;

    { int r = tid >> 6, c = tid & 63;      // exactly 1024 words
      maskS[r][c] = maskbits[(size_t)(q0 + r) * 64 + c]; }
    __syncthreads();

    const __bf16* vb = (const __bf16*)Vt_ + (size_t)h * FOUT * NN + kh * 2048;
    const float* dpb = d1 + h * NN + kh * 2048;
    const float A1 = a1v[h * NN + q0 + li];
    const float A2 = a2v[h * NN + q0 + li];

    float rs = 0.f;
    f32x4 acc[4];
#pragma unroll
    for (int n = 0; n < 4; ++n) acc[n] = (f32x4){0.f, 0.f, 0.f, 0.f};

    bf16x8 cvf[2][4], nvf[2][4];
#pragma unroll
    for (int n = 0; n < 4; ++n) {
        const __bf16* vp = vb + (size_t)(n * 16 + li) * NN + q * 8;
        cvf[0][n] = *(const bf16x8*)vp;
        cvf[1][n] = *(const bf16x8*)(vp + 32);
    }

    for (int kt = 0; kt < 32; ++kt) {
        int ktn = (kt + 1) & 31;           // wraps on last iter; harmless
#pragma unroll
        for (int n = 0; n < 4; ++n) {
            const __bf16* vp = vb + (size_t)(n * 16 + li) * NN + ktn * 64 + q * 8;
            nvf[0][n] = *(const bf16x8*)vp;
            nvf[1][n] = *(const bf16x8*)(vp + 32);
        }
        const float* dp = dpb + kt * 64 + q * 8;
        float dv[16];
        *(float4*)(dv + 0)  = *(const float4*)(dp);
        *(float4*)(dv + 4)  = *(const float4*)(dp + 4);
        *(float4*)(dv + 8)  = *(const float4*)(dp + 32);
        *(float4*)(dv + 12) = *(const float4*)(dp + 36);
        u64 mw = maskS[li][kh * 32 + kt];
        unsigned mlo = (unsigned)(mw >> (q * 8)) & 0xffu;
        unsigned mhi = (unsigned)(mw >> (q * 8 + 32)) & 0xffu;
        bf16x8 pf[2];
#pragma unroll
        for (int c = 0; c < 2; ++c) {
            unsigned mm = c ? mhi : mlo;
#pragma unroll
            for (int j = 0; j < 8; ++j) {
                float dj = dv[c * 8 + j];
                float e1 = A1 + dj;
                float e2 = fmaf(0.2f, dj, A2);
                float pv = __builtin_amdgcn_exp2f(fmaxf(e1, e2));   // arg <= 0 always
                pv = ((mm >> j) & 1u) ? pv : 0.f;
                rs += pv;
                pf[c][j] = (__bf16)pv;
            }
        }
#pragma unroll
        for (int c = 0; c < 2; ++c)
#pragma unroll
            for (int n = 0; n < 4; ++n)
                acc[n] = __builtin_amdgcn_mfma_f32_16x16x32_bf16(pf[c], cvf[c][n], acc[n], 0, 0, 0);
#pragma unroll
        for (int c = 0; c < 2; ++c)
#pragma unroll
            for (int n = 0; n < 4; ++n) cvf[c][n] = nvf[c][n];
    }

    rs += __shfl_xor(rs, 16);
    rs += __shfl_xor(rs, 32);
    if (q == 0) rsL[w][li] = rs;
    __syncthreads();

    float rinv[4];
#pragma unroll
    for (int reg = 0; reg < 4; ++reg) {
        int row = q * 4 + reg;
        rinv[reg] = 1.f / (rsL[2 * h][row] + rsL[2 * h + 1][row]);
    }
    if (kh == 1) {
#pragma unroll
        for (int n = 0; n < 4; ++n)
#pragma unroll
            for (int reg = 0; reg < 4; ++reg)
                stageB[h][q * 4 + reg][n * 16 + li] = acc[n][reg] * rinv[reg];
    }
    __syncthreads();
    if (kh == 0) {
#pragma unroll
        for (int n = 0; n < 4; ++n)
#pragma unroll
            for (int reg = 0; reg < 4; ++reg)
                stageB[h][q * 4 + reg][n * 16 + li] += acc[n][reg] * rinv[reg];
    }
    __syncthreads();

    {
        int rr = tid >> 6, cc = tid & 63;
        float s = 0.f;
#pragma unroll
        for (int h2 = 0; h2 < NH; ++h2) s += stageB[h2][rr][cc];
        float sk = skipm[(size_t)(q0 + rr) * FOUT + cc];
        float v = s * 0.125f + sk;
        v = fmaxf(v, 0.2f * v);
        out[(size_t)(q0 + rr) * FOUT + cc] = v;
    }
}

extern "C" void kernel_launch(void* const* d_in, const int* in_sizes, int n_in,
                              void* d_out, int out_size, void* d_ws, size_t ws_size,
                              hipStream_t stream) {
    (void)in_sizes; (void)n_in; (void)out_size; (void)ws_size;
    const float* x         = (const float*)d_in[0];   // [4096,128]
    const float* topology  = (const float*)d_in[1];   // [4096,4096]
    const float* proj      = (const float*)d_in[2];   // [8,128,64]
    const float* score_src = (const float*)d_in[3];   // [8,64]
    const float* score_dst = (const float*)d_in[4];   // [8,64]
    const float* skip_w    = (const float*)d_in[5];   // [512,128]
    float* out = (float*)d_out;                       // [4096,64]

    char* ws = (char*)d_ws;
    __hip_bfloat16* xb = (__hip_bfloat16*)ws;                 // 1 MB
    __hip_bfloat16* Vt = (__hip_bfloat16*)(ws + 1048576);     // 4 MB
    float* ssrc = (float*)(ws + 5242880);                     // 128 KB
    float* sdst = (float*)(ws + 5373952);                     // 128 KB
    float* d1   = (float*)(ws + 5505024);                     // 128 KB
    float* a1   = (float*)(ws + 5636096);                     // 128 KB
    float* a2   = (float*)(ws + 5767168);                     // 128 KB
    float* Wc   = (float*)(ws + 5898240);                     // 40 KB
    u64* maskbits = (u64*)(ws + 5939200);                     // 2 MB (end ~7.66 MB)
    float* skipm = out;   // skip GEMM result lives in d_out; attn epilogue consumes & overwrites

    wc_kernel<<<40, 256, 0, stream>>>(proj, score_src, score_dst, skip_w, Wc);
    scores_kernel<<<128, 256, 0, stream>>>(x, Wc, skipm, ssrc, sdst, xb);
    headprep_kernel<<<8, 256, 0, stream>>>(ssrc, sdst, d1, a1, a2);
    mask_kernel<<<2048, 256, 0, stream>>>(topology, maskbits);
    vt_kernel<<<512, 256, 0, stream>>>(proj, xb, Vt);
    attn_kernel<<<256, 1024, 0, stream>>>(maskbits, Vt, d1, a1, a2, skipm, out);
}

// Round 4
// 268.138 us; speedup vs baseline: 1.1457x; 1.0242x over previous
//
#include <hip/hip_runtime.h>
#include <hip/hip_bf16.h>

#define NN 4096
#define FIN 128
#define FOUT 64
#define NH 8

typedef float f32x4 __attribute__((ext_vector_type(4)));
typedef __bf16 bf16x8 __attribute__((ext_vector_type(8)));
typedef unsigned long long u64;

// ---------------- K0: build combined weights Wc[128][80]:
// cols 0..7 = proj[h]@score_src[h]; 8..15 = proj[h]@score_dst[h]; 16..79 = head-folded skip/8
__global__ __launch_bounds__(256) void wc_kernel(
    const float* __restrict__ proj, const float* __restrict__ score_src,
    const float* __restrict__ score_dst, const float* __restrict__ skip_w,
    float* __restrict__ Wc) {
    int idx = blockIdx.x * 256 + threadIdx.x;
    if (idx >= FIN * 80) return;
    int i = idx / 80, c = idx % 80;
    float v = 0.f;
    if (c < 16) {
        int h = c & 7;
        const float* w = (c < 8 ? score_src : score_dst) + h * FOUT;
        const float* p = proj + (size_t)h * FIN * FOUT + (size_t)i * FOUT;
        for (int f = 0; f < FOUT; ++f) v += p[f] * w[f];
    } else {
        int f = c - 16;
        for (int h = 0; h < NH; ++h) v += skip_w[(size_t)(h * FOUT + f) * FIN + i];
        v *= 0.125f;
    }
    Wc[i * 80 + c] = v;
}

// ---------------- K1: x@Wc -> skipm (in d_out), EF[h][n] (bf16-pair e^d, e^.2d),
// C12[h][n] (float2 e^s, e^.2s); also casts x->xb (bf16). No global max needed:
// scores are O(+-5) so e^score is fp32-safe; softmax normalizes scale away.
__global__ __launch_bounds__(256) void scores_kernel(
    const float* __restrict__ x, const float* __restrict__ Wc,
    float* __restrict__ skipm, unsigned* __restrict__ EF, float2* __restrict__ C12,
    __hip_bfloat16* __restrict__ xb_) {
    __shared__ float wcs[FIN][80];     // 40 KB
    __shared__ float xs[32][FIN + 5];  // 17 KB
    const int n0 = blockIdx.x * 32;
    const int tid = threadIdx.x;
    for (int i = tid; i < FIN * 80 / 4; i += 256)
        ((float4*)&wcs[0][0])[i] = ((const float4*)Wc)[i];
    const float4* xsrc = (const float4*)(x + (size_t)n0 * FIN);
    for (int i = tid; i < 32 * FIN / 4; i += 256) {
        int r = i >> 5, c4 = i & 31;
        *(float4*)&xs[r][c4 * 4] = xsrc[i];
    }
    __syncthreads();
    const int r = tid & 31;
    const int g = tid >> 5;        // 0..7
    const int f0 = g * 8;          // skip cols (of 64)
    const int c0 = g * 2;          // score cols (of 16)
    float acc[8];
    float sa0 = 0.f, sa1 = 0.f;
#pragma unroll
    for (int j = 0; j < 8; ++j) acc[j] = 0.f;
#pragma unroll 4
    for (int i = 0; i < FIN; ++i) {
        float xv = xs[r][i];
        float4 p0 = *(float4*)&wcs[i][16 + f0];
        float4 p1 = *(float4*)&wcs[i][16 + f0 + 4];
        float2 q0 = *(float2*)&wcs[i][c0];
        acc[0] += xv * p0.x; acc[1] += xv * p0.y; acc[2] += xv * p0.z; acc[3] += xv * p0.w;
        acc[4] += xv * p1.x; acc[5] += xv * p1.y; acc[6] += xv * p1.z; acc[7] += xv * p1.w;
        sa0 += xv * q0.x; sa1 += xv * q0.y;
    }
    int n = n0 + r;
#pragma unroll
    for (int j = 0; j < 8; ++j) skipm[(size_t)n * FOUT + f0 + j] = acc[j];
    if (c0 < 8) {
        C12[c0 * NN + n] = make_float2(expf(sa0), expf(0.2f * sa0));
        C12[(c0 + 1) * NN + n] = make_float2(expf(sa1), expf(0.2f * sa1));
    } else {
        __hip_bfloat16 e0 = __float2bfloat16(expf(sa0)), f0b = __float2bfloat16(expf(0.2f * sa0));
        __hip_bfloat16 e1 = __float2bfloat16(expf(sa1)), f1b = __float2bfloat16(expf(0.2f * sa1));
        EF[(c0 - 8) * NN + n] = ((unsigned)*(unsigned short*)&f0b << 16) | (unsigned)*(unsigned short*)&e0;
        EF[(c0 - 7) * NN + n] = ((unsigned)*(unsigned short*)&f1b << 16) | (unsigned)*(unsigned short*)&e1;
    }
    {
        int row = tid >> 3, col0 = (tid & 7) * 16;
        const float* src = &xs[row][col0];
        bf16x8 b0, b1;
#pragma unroll
        for (int j = 0; j < 8; ++j) { b0[j] = (__bf16)src[j]; b1[j] = (__bf16)src[8 + j]; }
        __bf16* dst = (__bf16*)xb_ + (size_t)(n0 + row) * FIN + col0;
        *(bf16x8*)dst = b0;
        *(bf16x8*)(dst + 8) = b1;
    }
}

// ---------------- K2: topology -> bitmask (bit=1 where edge), contiguous streaming
__global__ __launch_bounds__(256) void mask_kernel(
    const float* __restrict__ topo, u64* __restrict__ mb) {
    const int w = blockIdx.x * 4 + (threadIdx.x >> 6);   // 0..8191
    const int lane = threadIdx.x & 63;
    size_t base = (size_t)w * 32;
    for (int it = 0; it < 32; ++it) {
        size_t u = base + it;
        float t = topo[u * 64 + lane];
        u64 b = __ballot(t > -0.5e9f);
        if (lane == 0) mb[u] = b;
    }
}

// ---------------- K3: Vt[h][f][n] = (proj[h]^T @ x^T) via bf16 MFMA
__global__ __launch_bounds__(256) void vt_kernel(
    const float* __restrict__ proj, const __hip_bfloat16* __restrict__ xb_,
    __hip_bfloat16* __restrict__ Vt_) {
    __shared__ __bf16 pT[FOUT][FIN + 8];   // 17.4 KB
    const int tid = threadIdx.x;
    const int h = blockIdx.x >> 6;
    const int ng = blockIdx.x & 63;
    const __bf16* xb = (const __bf16*)xb_;
    __bf16* Vt = (__bf16*)Vt_;
    for (int idx = tid; idx < FIN * FOUT; idx += 256) {
        int i = idx >> 6, f = idx & 63;
        pT[f][i] = (__bf16)proj[(size_t)h * FIN * FOUT + idx];
    }
    __syncthreads();
    const int wave = tid >> 6, lane = tid & 63, q = lane >> 4, li = lane & 15;
    const int nb = ng * 64 + wave * 16;
    f32x4 acc[4];
#pragma unroll
    for (int n = 0; n < 4; ++n) acc[n] = (f32x4){0.f, 0.f, 0.f, 0.f};
#pragma unroll
    for (int kt = 0; kt < 4; ++kt) {
        bf16x8 bfrag = *(const bf16x8*)(xb + (size_t)(nb + li) * FIN + kt * 32 + q * 8);
#pragma unroll
        for (int ft = 0; ft < 4; ++ft) {
            bf16x8 afrag = *(const bf16x8*)&pT[ft * 16 + li][kt * 32 + q * 8];
            acc[ft] = __builtin_amdgcn_mfma_f32_16x16x32_bf16(afrag, bfrag, acc[ft], 0, 0, 0);
        }
    }
#pragma unroll
    for (int ft = 0; ft < 4; ++ft)
#pragma unroll
        for (int reg = 0; reg < 4; ++reg)
            Vt[((size_t)h * FOUT + ft * 16 + q * 4 + reg) * NN + nb + li] = (__bf16)acc[ft][reg];
}

// ---------------- K4: attention. 256 blocks x 1024 thr = 16 waves = (head, K-half).
// waves_per_eu(4,4) pins occupancy so the allocator keeps ~128 VGPRs: EF ping-pong
// survives and V loads hoist above the ~400-cyc VALU body. No transcendentals:
// p = max(C1*E, C2*F) with precomputed exponentials.
__attribute__((amdgpu_waves_per_eu(4, 4)))
__global__ __launch_bounds__(1024) void attn_kernel(
    const u64* __restrict__ maskbits, const __hip_bfloat16* __restrict__ Vt_,
    const unsigned* __restrict__ EF, const float2* __restrict__ C12,
    const float* __restrict__ skipm, float* __restrict__ out) {
    __shared__ u64 maskS[16][65];          // 8.3 KB
    __shared__ float rsL[16][17];
    __shared__ float stageB[NH][16][68];   // 34.8 KB
    const int tid = threadIdx.x;
    const int w = tid >> 6;                // 0..15
    const int h = w >> 1, kh = w & 1;
    const int lane = tid & 63, q = lane >> 4, li = lane & 15;
    const int q0 = blockIdx.x * 16;

    { int r = tid >> 6, c = tid & 63;
      maskS[r][c] = maskbits[(size_t)(q0 + r) * 64 + c]; }
    __syncthreads();

    const __bf16* vb = (const __bf16*)Vt_ + (size_t)h * FOUT * NN + kh * 2048;
    const unsigned* efb = EF + h * NN + kh * 2048;
    float2 c12 = C12[h * NN + q0 + li];
    const float C1 = c12.x, C2 = c12.y;

    float rs = 0.f;
    f32x4 acc[4];
#pragma unroll
    for (int n = 0; n < 4; ++n) acc[n] = (f32x4){0.f, 0.f, 0.f, 0.f};

    uint4 cef[4], nef[4];
    {
        const unsigned* ep = efb + q * 8;
        cef[0] = *(const uint4*)(ep);      cef[1] = *(const uint4*)(ep + 4);
        cef[2] = *(const uint4*)(ep + 32); cef[3] = *(const uint4*)(ep + 36);
    }

    for (int kt = 0; kt < 32; ++kt) {
        // prefetch next iteration's EF (distance = full body)
        int ktn = (kt + 1) & 31;
        const unsigned* ep = efb + ktn * 64 + q * 8;
        nef[0] = *(const uint4*)(ep);      nef[1] = *(const uint4*)(ep + 4);
        nef[2] = *(const uint4*)(ep + 32); nef[3] = *(const uint4*)(ep + 36);
        // V for current iteration, issued before the p-computation block
        bf16x8 cvf[2][4];
#pragma unroll
        for (int n = 0; n < 4; ++n) {
            const __bf16* vp = vb + (size_t)(n * 16 + li) * NN + kt * 64 + q * 8;
            cvf[0][n] = *(const bf16x8*)vp;
            cvf[1][n] = *(const bf16x8*)(vp + 32);
        }
        u64 mw = maskS[li][kh * 32 + kt];
        unsigned mlo = (unsigned)(mw >> (q * 8)) & 0xffu;
        unsigned mhi = (unsigned)(mw >> (q * 8 + 32)) & 0xffu;
        const unsigned* eu = (const unsigned*)cef;
        bf16x8 pf[2];
#pragma unroll
        for (int c = 0; c < 2; ++c) {
            unsigned mm = c ? mhi : mlo;
#pragma unroll
            for (int j = 0; j < 8; ++j) {
                unsigned e = eu[c * 8 + j];
                float E = __uint_as_float(e << 16);
                float F = __uint_as_float(e & 0xffff0000u);
                float pv = fmaxf(C1 * E, C2 * F);
                pv = ((mm >> j) & 1u) ? pv : 0.f;
                rs += pv;
                pf[c][j] = (__bf16)pv;
            }
        }
#pragma unroll
        for (int c = 0; c < 2; ++c)
#pragma unroll
            for (int n = 0; n < 4; ++n)
                acc[n] = __builtin_amdgcn_mfma_f32_16x16x32_bf16(pf[c], cvf[c][n], acc[n], 0, 0, 0);
#pragma unroll
        for (int u = 0; u < 4; ++u) cef[u] = nef[u];
    }

    rs += __shfl_xor(rs, 16);
    rs += __shfl_xor(rs, 32);
    if (q == 0) rsL[w][li] = rs;
    __syncthreads();

    float rinv[4];
#pragma unroll
    for (int reg = 0; reg < 4; ++reg) {
        int row = q * 4 + reg;
        rinv[reg] = 1.f / (rsL[2 * h][row] + rsL[2 * h + 1][row]);
    }
    if (kh == 1) {
#pragma unroll
        for (int n = 0; n < 4; ++n)
#pragma unroll
            for (int reg = 0; reg < 4; ++reg)
                stageB[h][q * 4 + reg][n * 16 + li] = acc[n][reg] * rinv[reg];
    }
    __syncthreads();
    if (kh == 0) {
#pragma unroll
        for (int n = 0; n < 4; ++n)
#pragma unroll
            for (int reg = 0; reg < 4; ++reg)
                stageB[h][q * 4 + reg][n * 16 + li] += acc[n][reg] * rinv[reg];
    }
    __syncthreads();

    {
        int rr = tid >> 6, cc = tid & 63;
        float s = 0.f;
#pragma unroll
        for (int h2 = 0; h2 < NH; ++h2) s += stageB[h2][rr][cc];
        float sk = skipm[(size_t)(q0 + rr) * FOUT + cc];
        float v = s * 0.125f + sk;
        v = fmaxf(v, 0.2f * v);
        out[(size_t)(q0 + rr) * FOUT + cc] = v;
    }
}

extern "C" void kernel_launch(void* const* d_in, const int* in_sizes, int n_in,
                              void* d_out, int out_size, void* d_ws, size_t ws_size,
                              hipStream_t stream) {
    (void)in_sizes; (void)n_in; (void)out_size; (void)ws_size;
    const float* x         = (const float*)d_in[0];   // [4096,128]
    const float* topology  = (const float*)d_in[1];   // [4096,4096]
    const float* proj      = (const float*)d_in[2];   // [8,128,64]
    const float* score_src = (const float*)d_in[3];   // [8,64]
    const float* score_dst = (const float*)d_in[4];   // [8,64]
    const float* skip_w    = (const float*)d_in[5];   // [512,128]
    float* out = (float*)d_out;                       // [4096,64]

    char* ws = (char*)d_ws;
    __hip_bfloat16* xb = (__hip_bfloat16*)ws;                 // 1 MB
    __hip_bfloat16* Vt = (__hip_bfloat16*)(ws + 1048576);     // 4 MB
    unsigned* EF  = (unsigned*)(ws + 5242880);                // 128 KB
    float2* C12   = (float2*)(ws + 5373952);                  // 256 KB
    float* Wc     = (float*)(ws + 5636096);                   // 40 KB
    u64* maskbits = (u64*)(ws + 5677056);                     // 2 MB (end ~7.41 MB)
    float* skipm = out;   // skip GEMM result lives in d_out; attn epilogue consumes & overwrites

    wc_kernel<<<40, 256, 0, stream>>>(proj, score_src, score_dst, skip_w, Wc);
    scores_kernel<<<128, 256, 0, stream>>>(x, Wc, skipm, EF, C12, xb);
    mask_kernel<<<2048, 256, 0, stream>>>(topology, maskbits);
    vt_kernel<<<512, 256, 0, stream>>>(proj, xb, Vt);
    attn_kernel<<<256, 1024, 0, stream>>>(maskbits, Vt, EF, C12, skipm, out);
}

// Round 5
// 203.271 us; speedup vs baseline: 1.5114x; 1.3191x over previous
//
#include <hip/hip_runtime.h>
#include <hip/hip_bf16.h>

#define NN 4096
#define FIN 128
#define FOUT 64
#define NH 8
#define KS 8          // K splits
#define KRANGE 512    // keys per block
#define QT 128        // Q rows per block

typedef float f32x4 __attribute__((ext_vector_type(4)));
typedef __bf16 bf16x8 __attribute__((ext_vector_type(8)));
typedef unsigned long long u64;

// ---------------- K0: combined weights Wc[128][80]:
// cols 0..7 = proj[h]@score_src[h]; 8..15 = proj[h]@score_dst[h]; 16..79 = head-folded skip/8
__global__ __launch_bounds__(256) void wc_kernel(
    const float* __restrict__ proj, const float* __restrict__ score_src,
    const float* __restrict__ score_dst, const float* __restrict__ skip_w,
    float* __restrict__ Wc) {
    int idx = blockIdx.x * 256 + threadIdx.x;
    if (idx >= FIN * 80) return;
    int i = idx / 80, c = idx % 80;
    float v = 0.f;
    if (c < 16) {
        int h = c & 7;
        const float* w = (c < 8 ? score_src : score_dst) + h * FOUT;
        const float* p = proj + (size_t)h * FIN * FOUT + (size_t)i * FOUT;
        for (int f = 0; f < FOUT; ++f) v += p[f] * w[f];
    } else {
        int f = c - 16;
        for (int h = 0; h < NH; ++h) v += skip_w[(size_t)(h * FOUT + f) * FIN + i];
        v *= 0.125f;
    }
    Wc[i * 80 + c] = v;
}

// ---------------- K1: x@Wc -> skipm (in d_out), EF (bf16-pair e^d,e^.2d), C12 (e^s,e^.2s), xb
__global__ __launch_bounds__(256) void scores_kernel(
    const float* __restrict__ x, const float* __restrict__ Wc,
    float* __restrict__ skipm, unsigned* __restrict__ EF, float2* __restrict__ C12,
    __hip_bfloat16* __restrict__ xb_) {
    __shared__ float wcs[FIN][80];
    __shared__ float xs[32][FIN + 5];
    const int n0 = blockIdx.x * 32;
    const int tid = threadIdx.x;
    for (int i = tid; i < FIN * 80 / 4; i += 256)
        ((float4*)&wcs[0][0])[i] = ((const float4*)Wc)[i];
    const float4* xsrc = (const float4*)(x + (size_t)n0 * FIN);
    for (int i = tid; i < 32 * FIN / 4; i += 256) {
        int r = i >> 5, c4 = i & 31;
        *(float4*)&xs[r][c4 * 4] = xsrc[i];
    }
    __syncthreads();
    const int r = tid & 31;
    const int g = tid >> 5;
    const int f0 = g * 8;
    const int c0 = g * 2;
    float acc[8];
    float sa0 = 0.f, sa1 = 0.f;
#pragma unroll
    for (int j = 0; j < 8; ++j) acc[j] = 0.f;
#pragma unroll 4
    for (int i = 0; i < FIN; ++i) {
        float xv = xs[r][i];
        float4 p0 = *(float4*)&wcs[i][16 + f0];
        float4 p1 = *(float4*)&wcs[i][16 + f0 + 4];
        float2 q0 = *(float2*)&wcs[i][c0];
        acc[0] += xv * p0.x; acc[1] += xv * p0.y; acc[2] += xv * p0.z; acc[3] += xv * p0.w;
        acc[4] += xv * p1.x; acc[5] += xv * p1.y; acc[6] += xv * p1.z; acc[7] += xv * p1.w;
        sa0 += xv * q0.x; sa1 += xv * q0.y;
    }
    int n = n0 + r;
#pragma unroll
    for (int j = 0; j < 8; ++j) skipm[(size_t)n * FOUT + f0 + j] = acc[j];
    if (c0 < 8) {
        C12[c0 * NN + n] = make_float2(expf(sa0), expf(0.2f * sa0));
        C12[(c0 + 1) * NN + n] = make_float2(expf(sa1), expf(0.2f * sa1));
    } else {
        __hip_bfloat16 e0 = __float2bfloat16(expf(sa0)), f0b = __float2bfloat16(expf(0.2f * sa0));
        __hip_bfloat16 e1 = __float2bfloat16(expf(sa1)), f1b = __float2bfloat16(expf(0.2f * sa1));
        EF[(c0 - 8) * NN + n] = ((unsigned)*(unsigned short*)&f0b << 16) | (unsigned)*(unsigned short*)&e0;
        EF[(c0 - 7) * NN + n] = ((unsigned)*(unsigned short*)&f1b << 16) | (unsigned)*(unsigned short*)&e1;
    }
    {
        int row = tid >> 3, col0 = (tid & 7) * 16;
        const float* src = &xs[row][col0];
        bf16x8 b0, b1;
#pragma unroll
        for (int j = 0; j < 8; ++j) { b0[j] = (__bf16)src[j]; b1[j] = (__bf16)src[8 + j]; }
        __bf16* dst = (__bf16*)xb_ + (size_t)(n0 + row) * FIN + col0;
        *(bf16x8*)dst = b0;
        *(bf16x8*)(dst + 8) = b1;
    }
}

// ---------------- K2: topology -> bitmask
__global__ __launch_bounds__(256) void mask_kernel(
    const float* __restrict__ topo, u64* __restrict__ mb) {
    const int w = blockIdx.x * 4 + (threadIdx.x >> 6);
    const int lane = threadIdx.x & 63;
    size_t base = (size_t)w * 32;
    for (int it = 0; it < 32; ++it) {
        size_t u = base + it;
        float t = topo[u * 64 + lane];
        u64 b = __ballot(t > -0.5e9f);
        if (lane == 0) mb[u] = b;
    }
}

// ---------------- K3: Vt[h][f][n] = proj[h]^T @ x^T via bf16 MFMA
__global__ __launch_bounds__(256) void vt_kernel(
    const float* __restrict__ proj, const __hip_bfloat16* __restrict__ xb_,
    __hip_bfloat16* __restrict__ Vt_) {
    __shared__ __bf16 pT[FOUT][FIN + 8];
    const int tid = threadIdx.x;
    const int h = blockIdx.x >> 6;
    const int ng = blockIdx.x & 63;
    const __bf16* xb = (const __bf16*)xb_;
    __bf16* Vt = (__bf16*)Vt_;
    for (int idx = tid; idx < FIN * FOUT; idx += 256) {
        int i = idx >> 6, f = idx & 63;
        pT[f][i] = (__bf16)proj[(size_t)h * FIN * FOUT + idx];
    }
    __syncthreads();
    const int wave = tid >> 6, lane = tid & 63, q = lane >> 4, li = lane & 15;
    const int nb = ng * 64 + wave * 16;
    f32x4 acc[4];
#pragma unroll
    for (int n = 0; n < 4; ++n) acc[n] = (f32x4){0.f, 0.f, 0.f, 0.f};
#pragma unroll
    for (int kt = 0; kt < 4; ++kt) {
        bf16x8 bfrag = *(const bf16x8*)(xb + (size_t)(nb + li) * FIN + kt * 32 + q * 8);
#pragma unroll
        for (int ft = 0; ft < 4; ++ft) {
            bf16x8 afrag = *(const bf16x8*)&pT[ft * 16 + li][kt * 32 + q * 8];
            acc[ft] = __builtin_amdgcn_mfma_f32_16x16x32_bf16(afrag, bfrag, acc[ft], 0, 0, 0);
        }
    }
#pragma unroll
    for (int ft = 0; ft < 4; ++ft)
#pragma unroll
        for (int reg = 0; reg < 4; ++reg)
            Vt[((size_t)h * FOUT + ft * 16 + q * 4 + reg) * NN + nb + li] = (__bf16)acc[ft][reg];
}

// ---------------- K4: attention with LDS-staged V (global_load_lds), k-split partials.
// grid = 32 q-tiles x 8 k-splits; block 512 thr = 8 waves; wave w owns rows w*16..w*16+15.
// Per iteration (128 keys): each wave DMAs 2 KB of V into LDS; all waves share the tile.
__global__ __launch_bounds__(512, 2) void attn_kernel(
    const u64* __restrict__ maskbits, const __hip_bfloat16* __restrict__ Vt_,
    const unsigned* __restrict__ EFg, const float2* __restrict__ C12g,
    __hip_bfloat16* __restrict__ accP, float* __restrict__ rsP) {
    __shared__ __bf16 vS[2][2][64][64];     // 32 KB: [buf][sub][f][k] (k XOR-swizzled)
    __shared__ u64 maskS[QT][9];            // 9.2 KB
    __shared__ unsigned EFs[NH * KRANGE];   // 16 KB
    const int tid = threadIdx.x;
    const int w = tid >> 6, lane = tid & 63, q = lane >> 4, li = lane & 15;
    const int qt = blockIdx.x >> 3, ks = blockIdx.x & 7;
    const int row0 = qt * QT;
    const int kb0 = ks * KRANGE;

    const int fg = lane >> 3, k8 = lane & 7;       // DMA decomposition
    const int swz = ((k8 + fg) & 7) * 8;           // per-row key rotation
    const __bf16* VtB = (const __bf16*)Vt_;

    auto stage = [&](int gg) {                     // gg = h*4 + T
        int h = gg >> 2, T = gg & 3;
        const __bf16* gsrc = VtB + (size_t)h * (FOUT * NN)
                             + (size_t)(w * 8 + fg) * NN + kb0 + T * 128;
        char* lb0 = (char*)&vS[gg & 1][0][w * 8][0];
        char* lb1 = (char*)&vS[gg & 1][1][w * 8][0];
        __builtin_amdgcn_global_load_lds(
            (const __attribute__((address_space(1))) void*)(gsrc + swz),
            (__attribute__((address_space(3))) void*)lb0, 16, 0, 0);
        __builtin_amdgcn_global_load_lds(
            (const __attribute__((address_space(1))) void*)(gsrc + 64 + swz),
            (__attribute__((address_space(3))) void*)lb1, 16, 0, 0);
    };

    stage(0);   // start DMA early
    for (int i = tid; i < 1024; i += 512) {        // mask: 128 rows x 8 words
        int r = i >> 3, wd = i & 7;
        maskS[r][wd] = maskbits[(size_t)(row0 + r) * 64 + ks * 8 + wd];
    }
    for (int i = tid; i < 1024; i += 512) {        // EF: 8 heads x 512 keys
        int h = i >> 7, k4 = (i & 127) * 4;
        *(uint4*)&EFs[h * KRANGE + k4] = *(const uint4*)&EFg[(size_t)h * NN + kb0 + k4];
    }
    __syncthreads();                               // drains stage(0) + LDS writes

#pragma unroll 1
    for (int h = 0; h < NH; ++h) {
        float2 c12 = C12g[(size_t)h * NN + row0 + w * 16 + li];
        const float C1 = c12.x, C2 = c12.y;
        float rs = 0.f;
        f32x4 acc[4];
#pragma unroll
        for (int n = 0; n < 4; ++n) acc[n] = (f32x4){0.f, 0.f, 0.f, 0.f};

#pragma unroll
        for (int T = 0; T < 4; ++T) {
            int gg = h * 4 + T;
            if (gg < 31) stage(gg + 1);
#pragma unroll
            for (int s = 0; s < 2; ++s) {
                u64 mw = maskS[w * 16 + li][T * 2 + s];
                unsigned mlo = (unsigned)(mw >> (q * 8)) & 0xffu;
                unsigned mhi = (unsigned)((mw >> 32) >> (q * 8)) & 0xffu;
                const unsigned* efp = &EFs[h * KRANGE + T * 128 + s * 64];
                uint4 ea = *(const uint4*)&efp[q * 8];
                uint4 eb = *(const uint4*)&efp[q * 8 + 4];
                uint4 ec = *(const uint4*)&efp[32 + q * 8];
                uint4 ed = *(const uint4*)&efp[32 + q * 8 + 4];
                unsigned ew[16] = {ea.x, ea.y, ea.z, ea.w, eb.x, eb.y, eb.z, eb.w,
                                   ec.x, ec.y, ec.z, ec.w, ed.x, ed.y, ed.z, ed.w};
                bf16x8 pf[2];
#pragma unroll
                for (int c = 0; c < 2; ++c) {
                    unsigned mm = c ? mhi : mlo;
#pragma unroll
                    for (int j = 0; j < 8; ++j) {
                        unsigned e = ew[c * 8 + j];
                        float E = __uint_as_float(e << 16);
                        float F = __uint_as_float(e & 0xffff0000u);
                        float pv = fmaxf(C1 * E, C2 * F);
                        pv = ((mm >> j) & 1u) ? pv : 0.f;
                        rs += pv;
                        pf[c][j] = (__bf16)pv;
                    }
                }
#pragma unroll
                for (int c = 0; c < 2; ++c)
#pragma unroll
                    for (int n = 0; n < 4; ++n) {
                        int slot = ((c * 4 + q) - li) & 7;   // un-swizzle
                        bf16x8 vf = *(const bf16x8*)&vS[gg & 1][s][n * 16 + li][slot * 8];
                        acc[n] = __builtin_amdgcn_mfma_f32_16x16x32_bf16(pf[c], vf, acc[n], 0, 0, 0);
                    }
            }
            __syncthreads();   // drains prefetch DMA; protects buffer reuse
        }

        // per-head epilogue: unnormalized partials
        rs += __shfl_xor(rs, 16);
        rs += __shfl_xor(rs, 32);
        if (q == 0) rsP[(size_t)(ks * NH + h) * NN + row0 + w * 16 + li] = rs;
        __hip_bfloat16* ap = accP + ((size_t)(ks * NH + h) * NN + row0 + w * 16) * 64;
#pragma unroll
        for (int n = 0; n < 4; ++n)
#pragma unroll
            for (int reg = 0; reg < 4; ++reg)
                ap[(q * 4 + reg) * 64 + n * 16 + li] = __float2bfloat16(acc[n][reg]);
    }
}

// ---------------- K5: combine k-split partials + mean heads + skip + LeakyReLU
__global__ __launch_bounds__(256) void combine_kernel(
    const __hip_bfloat16* __restrict__ accP, const float* __restrict__ rsP,
    float* __restrict__ out) {
    int idx = blockIdx.x * 256 + threadIdx.x;      // 262144
    int row = idx >> 6, f = idx & 63;
    float s = 0.f;
#pragma unroll 1
    for (int h = 0; h < NH; ++h) {
        float a = 0.f, r = 0.f;
#pragma unroll
        for (int k = 0; k < KS; ++k) {
            a += __bfloat162float(accP[((size_t)(k * NH + h) * NN + row) * 64 + f]);
            r += rsP[(size_t)(k * NH + h) * NN + row];
        }
        s += a / r;
    }
    float v = s * 0.125f + out[idx];               // out currently holds skipm
    out[idx] = fmaxf(v, 0.2f * v);
}

extern "C" void kernel_launch(void* const* d_in, const int* in_sizes, int n_in,
                              void* d_out, int out_size, void* d_ws, size_t ws_size,
                              hipStream_t stream) {
    (void)in_sizes; (void)n_in; (void)out_size; (void)ws_size;
    const float* x         = (const float*)d_in[0];   // [4096,128]
    const float* topology  = (const float*)d_in[1];   // [4096,4096]
    const float* proj      = (const float*)d_in[2];   // [8,128,64]
    const float* score_src = (const float*)d_in[3];   // [8,64]
    const float* score_dst = (const float*)d_in[4];   // [8,64]
    const float* skip_w    = (const float*)d_in[5];   // [512,128]
    float* out = (float*)d_out;                       // [4096,64]

    char* ws = (char*)d_ws;
    __hip_bfloat16* xb = (__hip_bfloat16*)ws;                 // 1 MB
    __hip_bfloat16* Vt = (__hip_bfloat16*)(ws + 1048576);     // 4 MB
    unsigned* EF  = (unsigned*)(ws + 5242880);                // 128 KB
    float2* C12   = (float2*)(ws + 5373952);                  // 256 KB
    float* Wc     = (float*)(ws + 5636096);                   // 40 KB
    u64* maskbits = (u64*)(ws + 5677056);                     // 2 MB
    float* rsP    = (float*)(ws + 7774208);                   // 1 MB
    __hip_bfloat16* accP = (__hip_bfloat16*)(ws + 8822784);   // 32 MB (end ~42.4 MB)
    float* skipm = out;   // skip GEMM lives in d_out; combine consumes & overwrites

    wc_kernel<<<40, 256, 0, stream>>>(proj, score_src, score_dst, skip_w, Wc);
    scores_kernel<<<128, 256, 0, stream>>>(x, Wc, skipm, EF, C12, xb);
    mask_kernel<<<2048, 256, 0, stream>>>(topology, maskbits);
    vt_kernel<<<512, 256, 0, stream>>>(proj, xb, Vt);
    attn_kernel<<<256, 512, 0, stream>>>(maskbits, Vt, EF, C12, accP, rsP);
    combine_kernel<<<1024, 256, 0, stream>>>(accP, rsP, out);
}